// Round 9
// baseline (668.120 us; speedup 1.0000x reference)
//
#include <hip/hip_runtime.h>
#include <hip/hip_bf16.h>
#include <hip/hip_cooperative_groups.h>

namespace cg = cooperative_groups;

namespace {

constexpr int N = 50000;
constexpr int E = 300000;
constexpr int G = 256;
constexpr int H = 256;
constexpr float EPS = 1e-5f;
constexpr int NB = (N + 255) / 256;   // 196 scan blocks
constexpr int POOL_S = 16;
constexpr int GBL = 256;              // gnn grid: 1 block per CU (132KB LDS)
constexpr int NVB = N / 16;           // 3125 node-groups of 16
constexpr float LOG2E = 1.4426950408889634f;
constexpr float LN2   = 0.6931471805599453f;

typedef unsigned short u16;
typedef __attribute__((ext_vector_type(8))) short bf16x8;
typedef __attribute__((ext_vector_type(4))) float f32x4;

__device__ __forceinline__ float expnabs(float z){
  float r; asm("v_exp_f32 %0, -abs(%1)" : "=v"(r) : "v"(z)); return r;
}
__device__ __forceinline__ float log2f_(float x){
  float r; asm("v_log_f32 %0, %1" : "=v"(r) : "v"(x)); return r;
}
// scaled softplus: input z' = z*log2e; returns log2e*softplus(z)
__device__ __forceinline__ float spw(float zs){
  return fmaxf(zs, 0.f) + log2f_(1.f + expnabs(zs));
}
__device__ __forceinline__ u16 f2b(float f){
  union { float f; unsigned u; } v; v.f = f;
  unsigned r = v.u + 0x7FFF + ((v.u >> 16) & 1);
  return (u16)(r >> 16);
}
__device__ __forceinline__ float b2f(u16 u){
  union { unsigned i; float f; } v; v.i = ((unsigned)u) << 16; return v.f;
}
__device__ __forceinline__ float4 b2f4(ushort4 u){
  return make_float4(b2f(u.x), b2f(u.y), b2f(u.z), b2f(u.w));
}
__device__ __forceinline__ ushort4 f2b4(float4 v){
  ushort4 o; o.x = f2b(v.x); o.y = f2b(v.y); o.z = f2b(v.z); o.w = f2b(v.w);
  return o;
}

// async global->LDS, 16B per lane; LDS dest must be wave-uniform base (+lane*16 implicit)
__device__ __forceinline__ void gl_lds16(const u16* g, u16* l){
  __builtin_amdgcn_global_load_lds(
      (const __attribute__((address_space(1))) unsigned int*)g,
      (__attribute__((address_space(3))) unsigned int*)l, 16, 0, 0);
}

// merged prologue: embed (scaled bf16) | edge histogram | weight conversion | eemb*log2e
__global__ void k_pre(const int* __restrict__ nt, const float* __restrict__ nemb,
                      u16* __restrict__ xb, const int* __restrict__ dst,
                      int* __restrict__ cnt,
                      const float* __restrict__ W1, const float* __restrict__ W2,
                      const float* __restrict__ W3, const float* __restrict__ eemb,
                      u16* __restrict__ Wt1, u16* __restrict__ Wt2,
                      u16* __restrict__ Wt3, float* __restrict__ eembF){
  int idx = blockIdx.x * 256 + threadIdx.x;
  if (idx < N * 64){
    int i = idx >> 6, fq = (idx & 63) << 2;
    float4 v = *(const float4*)(nemb + (size_t)nt[i] * H + fq);
    v.x *= LOG2E; v.y *= LOG2E; v.z *= LOG2E; v.w *= LOG2E;
    *(ushort4*)(xb + (size_t)i * H + fq) = f2b4(v);
    return;
  }
  int j = idx - N * 64;
  if (j < E){ atomicAdd(&cnt[dst[j]], 1); return; }
  j -= E;
  if (j < 65536){ int c = j >> 8, k = j & 255; Wt1[j] = f2b(W1[(size_t)k * 256 + c]); return; }
  j -= 65536;
  if (j < 32768){ int c = j >> 8, k = j & 255; Wt2[j] = f2b(W2[(size_t)k * 128 + c]); return; }
  j -= 32768;
  if (j < 16384){ int c = j >> 7, k = j & 127; Wt3[j] = f2b(W3[(size_t)k * 128 + c]); return; }
  j -= 16384;
  if (j < 25600) eembF[j] = eemb[j] * LOG2E;
}

// ---- CSR scan ----
__global__ void k_scan1(const int* __restrict__ cnt, int* __restrict__ bsum){
  __shared__ int s[256];
  int t = threadIdx.x;
  int i = blockIdx.x * 256 + t;
  s[t] = (i < N) ? cnt[i] : 0;
  __syncthreads();
  for (int d = 128; d > 0; d >>= 1){
    if (t < d) s[t] += s[t + d];
    __syncthreads();
  }
  if (t == 0) bsum[blockIdx.x] = s[0];
}

__global__ void k_scan2(const int* __restrict__ bsum, int* __restrict__ bbase){
  __shared__ int s[256];
  int t = threadIdx.x;
  int orig = (t < NB) ? bsum[t] : 0;
  s[t] = orig;
  __syncthreads();
  for (int d = 1; d < 256; d <<= 1){
    int v = (t >= d) ? s[t - d] : 0;
    __syncthreads();
    s[t] += v;
    __syncthreads();
  }
  bbase[t] = s[t] - orig;   // exclusive
}

__global__ void k_scan3(const int* __restrict__ cnt, const int* __restrict__ bbase,
                        int* __restrict__ off, int* __restrict__ cur){
  __shared__ int s[256];
  int t = threadIdx.x;
  int i = blockIdx.x * 256 + t;
  int v = (i < N) ? cnt[i] : 0;
  s[t] = v;
  __syncthreads();
  for (int d = 1; d < 256; d <<= 1){
    int u = (t >= d) ? s[t - d] : 0;
    __syncthreads();
    s[t] += u;
    __syncthreads();
  }
  int excl = bbase[blockIdx.x] + s[t] - v;
  if (i < N){ off[i] = excl; cur[i] = excl; }
  if (i == N - 1) off[N] = excl + v;   // == E
}

// edges_s[p] = (src*512, et*1024): byte offsets into bf16 rows / fp32 eembF rows
__global__ void k_fill(const int* __restrict__ src, const int* __restrict__ dst,
                       const int* __restrict__ et, int* __restrict__ cur,
                       int2* __restrict__ edges_s){
  int e = blockIdx.x * 256 + threadIdx.x;
  if (e >= E) return;
  int d = dst[e];
  int p = atomicAdd(&cur[d], 1);
  edges_s[p] = make_int2(src[e] << 9, et[e] << 10);
}

__device__ __forceinline__ void acc_w(float4& acc, const float4 xs, const float4 es){
  acc.x += spw(xs.x + es.x);
  acc.y += spw(xs.y + es.y);
  acc.z += spw(xs.z + es.z);
  acc.w += spw(xs.w + es.w);
}

// Cooperative 3-layer GNN: per layer {gather+stats -> grid.sync -> BN-apply -> grid.sync}.
// Gather body is the measured-best round-4 form (f32 eembF in LDS, 1 node/wave).
// eembF staged ONCE for all three layers. xb holds activated input; agg holds raw output.
__global__ __launch_bounds__(1024)
void k_gnn(u16* __restrict__ xb, u16* __restrict__ agg,
           const int2* __restrict__ edges_s, const int* __restrict__ off,
           const float* __restrict__ eembF, float* __restrict__ statsA,
           const float* __restrict__ g0, const float* __restrict__ b0,
           const float* __restrict__ g1, const float* __restrict__ b1,
           const float* __restrict__ g2, const float* __restrict__ b2){
  cg::grid_group grid = cg::this_grid();
  __shared__ __align__(16) float elds[25600];     // 100 KB: eembF table (staged once)
  __shared__ float reds[1024][4];                 // 16 KB
  __shared__ float reds2[1024][4];                // 16 KB
  int tid = threadIdx.x;
  int w = tid >> 6, lane = tid & 63;
  int fx = lane << 3, fe = lane << 4;
  const char* eL = (const char*)elds;

  // stage eembF -> LDS (6400 float4)
  {
    const float4* s4 = (const float4*)eembF;
    float4* d4 = (float4*)elds;
    for (int t = tid; t < 6400; t += 1024) d4[t] = s4[t];
  }
  __syncthreads();

  const float inv = 1.f / N;
  for (int l = 0; l < 3; ++l){
    float* sums  = statsA + l * 512;
    float* sumsq = sums + 256;
    const char* xB = (const char*)xb;

    // ---- gather layer l: read activated xb -> raw agg, accumulate stats ----
    float4 ls = make_float4(0.f, 0.f, 0.f, 0.f);
    float4 ls2 = make_float4(0.f, 0.f, 0.f, 0.f);
    for (int vb = blockIdx.x; vb < NVB; vb += GBL){
      int i = vb * 16 + w;
      float4 acc = b2f4(*(const ushort4*)(xB + ((size_t)i << 9) + fx));
      int lo = off[i], hi = off[i + 1];
      int j = lo;
      for (; j + 4 <= hi; j += 4){
        int2 s0 = edges_s[j + 0];
        int2 s1 = edges_s[j + 1];
        int2 s2 = edges_s[j + 2];
        int2 s3 = edges_s[j + 3];
        ushort4 x0 = *(const ushort4*)(xB + s0.x + fx);
        ushort4 x1 = *(const ushort4*)(xB + s1.x + fx);
        ushort4 x2 = *(const ushort4*)(xB + s2.x + fx);
        ushort4 x3 = *(const ushort4*)(xB + s3.x + fx);
        float4 e0 = *(const float4*)(eL + s0.y + fe);
        float4 e1 = *(const float4*)(eL + s1.y + fe);
        float4 e2 = *(const float4*)(eL + s2.y + fe);
        float4 e3 = *(const float4*)(eL + s3.y + fe);
        acc_w(acc, b2f4(x0), e0);
        acc_w(acc, b2f4(x1), e1);
        acc_w(acc, b2f4(x2), e2);
        acc_w(acc, b2f4(x3), e3);
      }
      if (j + 2 <= hi){
        int2 s0 = edges_s[j + 0];
        int2 s1 = edges_s[j + 1];
        ushort4 x0 = *(const ushort4*)(xB + s0.x + fx);
        ushort4 x1 = *(const ushort4*)(xB + s1.x + fx);
        float4 e0 = *(const float4*)(eL + s0.y + fe);
        float4 e1 = *(const float4*)(eL + s1.y + fe);
        acc_w(acc, b2f4(x0), e0);
        acc_w(acc, b2f4(x1), e1);
        j += 2;
      }
      if (j < hi){
        int2 s0 = edges_s[j];
        ushort4 x0 = *(const ushort4*)(xB + s0.x + fx);
        float4 e0 = *(const float4*)(eL + s0.y + fe);
        acc_w(acc, b2f4(x0), e0);
      }
      acc.x *= LN2; acc.y *= LN2; acc.z *= LN2; acc.w *= LN2;
      ls.x += acc.x; ls.y += acc.y; ls.z += acc.z; ls.w += acc.w;
      ls2.x += acc.x * acc.x; ls2.y += acc.y * acc.y;
      ls2.z += acc.z * acc.z; ls2.w += acc.w * acc.w;
      *(ushort4*)((char*)agg + ((size_t)i << 9) + fx) = f2b4(acc);
    }
    reds[tid][0] = ls.x;  reds[tid][1] = ls.y;  reds[tid][2] = ls.z;  reds[tid][3] = ls.w;
    reds2[tid][0] = ls2.x; reds2[tid][1] = ls2.y; reds2[tid][2] = ls2.z; reds2[tid][3] = ls2.w;
    __syncthreads();
    if (tid < 256){
      int f = tid;
      float ts = 0.f, ts2 = 0.f;
      #pragma unroll
      for (int w2 = 0; w2 < 16; ++w2){
        int s = w2 * 64 + (f >> 2);
        ts += reds[s][f & 3];
        ts2 += reds2[s][f & 3];
      }
      atomicAdd(&sums[f], ts);
      atomicAdd(&sumsq[f], ts2);
    }
    grid.sync();

    // ---- BN-apply layer l: raw agg -> xb (l<2: spw-activated scaled; l==2: plain BN) ----
    const float* gamma = (l == 0) ? g0 : (l == 1) ? g1 : g2;
    const float* beta  = (l == 0) ? b0 : (l == 1) ? b1 : b2;
    for (int idx = blockIdx.x * 1024 + tid; idx < N * 64; idx += GBL * 1024){
      int base = idx << 2;
      int f = base & 255;
      float4 s = *(const float4*)(sums + f);
      float4 q = *(const float4*)(sumsq + f);
      float4 g = *(const float4*)(gamma + f);
      float4 bt = *(const float4*)(beta + f);
      float4 v = b2f4(*(const ushort4*)(agg + base));
      float m, var, a, c;
      m = s.x * inv; var = q.x * inv - m * m; a = g.x * rsqrtf(var + EPS); c = bt.x - m * a; v.x = a * v.x + c;
      m = s.y * inv; var = q.y * inv - m * m; a = g.y * rsqrtf(var + EPS); c = bt.y - m * a; v.y = a * v.y + c;
      m = s.z * inv; var = q.z * inv - m * m; a = g.z * rsqrtf(var + EPS); c = bt.z - m * a; v.z = a * v.z + c;
      m = s.w * inv; var = q.w * inv - m * m; a = g.w * rsqrtf(var + EPS); c = bt.w - m * a; v.w = a * v.w + c;
      if (l < 2){
        v.x = spw(v.x * LOG2E); v.y = spw(v.y * LOG2E);
        v.z = spw(v.z * LOG2E); v.w = spw(v.w * LOG2E);
      }
      *(ushort4*)(xb + base) = f2b4(v);
    }
    grid.sync();
  }
}

// BN-apply, bf16 in -> bf16 out. ACT: softplus. SCALED: output *log2e (for gather input).
template<int ACT, int SCALED>
__global__ void k_norm(const u16* __restrict__ in, u16* __restrict__ outb,
                       const float* __restrict__ sums, const float* __restrict__ sumsq,
                       const float* __restrict__ gamma, const float* __restrict__ beta,
                       int n4, int fmask){
  int idx = blockIdx.x * 256 + threadIdx.x;
  if (idx >= n4) return;
  int base = idx << 2;
  int f = base & fmask;
  float4 s = *(const float4*)(sums + f);
  float4 q = *(const float4*)(sumsq + f);
  float4 g = *(const float4*)(gamma + f);
  float4 bt = *(const float4*)(beta + f);
  float4 v = b2f4(*(const ushort4*)(in + base));
  const float inv = 1.f / N;
  float m, var, a, c;
  m = s.x * inv; var = q.x * inv - m * m; a = g.x * rsqrtf(var + EPS); c = bt.x - m * a; v.x = a * v.x + c;
  m = s.y * inv; var = q.y * inv - m * m; a = g.y * rsqrtf(var + EPS); c = bt.y - m * a; v.y = a * v.y + c;
  m = s.z * inv; var = q.z * inv - m * m; a = g.z * rsqrtf(var + EPS); c = bt.z - m * a; v.z = a * v.z + c;
  m = s.w * inv; var = q.w * inv - m * m; a = g.w * rsqrtf(var + EPS); c = bt.w - m * a; v.w = a * v.w + c;
  if (ACT){
    v.x = spw(v.x * LOG2E); v.y = spw(v.y * LOG2E);
    v.z = spw(v.z * LOG2E); v.w = spw(v.w * LOG2E);
    if (!SCALED){ v.x *= LN2; v.y *= LN2; v.z *= LN2; v.w *= LN2; }
  }
  *(ushort4*)(outb + base) = f2b4(v);
}

// segmented pool over (unscaled) bf16 features: grid (G, POOL_S)
__global__ void k_pool_seg(const u16* __restrict__ xb, const int* __restrict__ batch,
                           float* __restrict__ hg){
  int g = blockIdx.x, sl = blockIdx.y;
  int f = threadIdx.x;
  int lo = 0, hi = N;
  while (lo < hi){ int m = (lo + hi) >> 1; if (batch[m] < g) lo = m + 1; else hi = m; }
  int start = lo;
  lo = 0; hi = N;
  while (lo < hi){ int m = (lo + hi) >> 1; if (batch[m] < g + 1) lo = m + 1; else hi = m; }
  int end = lo;
  int len = end - start;
  int a = start + (int)((long)len * sl / POOL_S);
  int b = start + (int)((long)len * (sl + 1) / POOL_S);
  if (a >= b) return;
  float s = 0.f;
  for (int i = a; i < b; ++i) s += b2f(xb[(size_t)i * H + f]);
  atomicAdd(&hg[g * H + f], s);
}

// hgW[g][c] = sum_k hg[g][k] * W1[256+k][c] + B1[c]
__global__ void k_hgw(const float* __restrict__ hg, const float* __restrict__ W1,
                      const float* __restrict__ B1, float* __restrict__ hgW){
  int g = blockIdx.x, c = threadIdx.x;
  float acc = B1[c];
  for (int k = 0; k < H; ++k)
    acc += hg[g * H + k] * W1[(size_t)(H + k) * H + c];
  hgW[g * H + c] = acc;
}

// LDS-staged double-buffered MFMA GEMM. Block = 128 rows x 128 cols, 4 waves (64x64/wave).
// MODE 0: += hgW[batch[row]] -> bf16; MODE 1: += bias -> bf16; MODE 2: += bias -> split fp32.
template<int K, int NCOUT, int MODE, int STATS>
__global__ __launch_bounds__(256)
void k_mgemm(const u16* __restrict__ Ab, const u16* __restrict__ Wt,
             const float* __restrict__ epi, const int* __restrict__ batch,
             u16* __restrict__ outb, float* __restrict__ outf,
             float* __restrict__ sums, float* __restrict__ sumsq){
  constexpr int T = K / 64;                     // k-tiles
  // smem: A[2][128][64] | B[2][128][64]  (u16), 64 KB total
  __shared__ __align__(16) u16 smem[32768];
  int tid = threadIdx.x;
  int w = tid >> 6, lane = tid & 63;
  int quad = lane >> 4, l15 = lane & 15;
  int wr = w >> 1, wc = w & 1;                  // 2x2 waves
  int rowBase = blockIdx.x * 128 + wr * 64;
  int colTile = blockIdx.y * 128;
  const u16* Ag = Ab + (size_t)blockIdx.x * 128 * K;
  const u16* Bg = Wt + (size_t)colTile * K;

  // stage one 128x64 tile (4 issues of 256 lanes x 16B), source pre-swizzled
  int w6 = tid & 192;                           // wave-uniform wave base
  auto stage = [&](const u16* gbase, u16* lbuf){
    #pragma unroll
    for (int it = 0; it < 4; ++it){
      int p = it * 256 + tid;                   // 16B-unit index
      int row = p >> 3, slot = p & 7;
      const u16* g = gbase + (size_t)row * K + ((slot ^ (row & 7)) << 3);
      gl_lds16(g, smem + ((size_t)((lbuf - smem) + (((it * 256 + w6)) << 3))));
    }
  };

  stage(Ag, smem);                              // A tile 0 -> buf0
  stage(Bg, smem + 16384);                      // B tile 0 -> buf0

  f32x4 acc[4][4] = {};
  int xb7 = l15 & 7;
  for (int tt = 0; tt < T; ++tt){
    if (tt + 1 < T){
      int nb = (tt + 1) & 1;
      stage(Ag + (tt + 1) * 64, smem + nb * 8192);
      stage(Bg + (tt + 1) * 64, smem + 16384 + nb * 8192);
    }
    __syncthreads();                            // drains DMA (vmcnt0) + sync
    const u16* lA = smem + (tt & 1) * 8192;
    const u16* lB = smem + 16384 + (tt & 1) * 8192;
    #pragma unroll
    for (int ks = 0; ks < 2; ++ks){
      int xs = (((ks << 2) | quad) ^ xb7) << 3;
      bf16x8 a[4], b[4];
      #pragma unroll
      for (int t = 0; t < 4; ++t)
        a[t] = *(const bf16x8*)(lA + ((wr * 64 + t * 16 + l15) << 6) + xs);
      #pragma unroll
      for (int u = 0; u < 4; ++u)
        b[u] = *(const bf16x8*)(lB + ((wc * 64 + u * 16 + l15) << 6) + xs);
      #pragma unroll
      for (int t = 0; t < 4; ++t)
        #pragma unroll
        for (int u = 0; u < 4; ++u)
          acc[t][u] = __builtin_amdgcn_mfma_f32_16x16x32_bf16(a[t], b[u], acc[t][u], 0, 0, 0);
    }
    __syncthreads();                            // all reads done before next overwrite
  }

  int colBase = colTile + wc * 64;
  float ls[4] = {0.f, 0.f, 0.f, 0.f};
  float ls2[4] = {0.f, 0.f, 0.f, 0.f};
  #pragma unroll
  for (int t = 0; t < 4; ++t){
    #pragma unroll
    for (int r = 0; r < 4; ++r){
      int row = rowBase + t * 16 + quad * 4 + r;
      if (row >= N) continue;
      int g = (MODE == 0) ? batch[row] : 0;
      #pragma unroll
      for (int u = 0; u < 4; ++u){
        int n = colBase + u * 16 + l15;
        float v = acc[t][u][r];
        if (MODE == 0){
          v += epi[(size_t)g * NCOUT + n];
          outb[(size_t)row * NCOUT + n] = f2b(v);
        } else if (MODE == 1){
          v += epi[n];
          outb[(size_t)row * NCOUT + n] = f2b(v);
        } else {
          v += epi[n];
          if (n < 64) outf[(size_t)row * 64 + n] = v;
          else        outf[(size_t)N * 64 + (size_t)row * 64 + (n - 64)] = v;
        }
        if (STATS){ ls[u] += v; ls2[u] += v * v; }
      }
    }
  }
  if (STATS){
    // reuse tile LDS for the stats reduction (tiles fully consumed, barrier'd)
    float (*reds)[4]  = (float (*)[4])smem;           // 4 KB
    float (*reds2)[4] = (float (*)[4])(smem + 2048);  // next 4 KB
    #pragma unroll
    for (int u = 0; u < 4; ++u){ reds[tid][u] = ls[u]; reds2[tid][u] = ls2[u]; }
    __syncthreads();
    int f = tid;
    if (f < 128){
      int fl = f & 15, fu = (f >> 4) & 3, fw = f >> 6;  // fw = wc
      float ts = 0.f, ts2 = 0.f;
      #pragma unroll
      for (int r2 = 0; r2 < 2; ++r2)
        #pragma unroll
        for (int q = 0; q < 4; ++q){
          int s = (r2 * 2 + fw) * 64 + q * 16 + fl;
          ts += reds[s][fu]; ts2 += reds2[s][fu];
        }
      atomicAdd(&sums[colTile + f], ts);
      atomicAdd(&sumsq[colTile + f], ts2);
    }
  }
}

} // namespace

extern "C" void kernel_launch(void* const* d_in, const int* in_sizes, int n_in,
                              void* d_out, int out_size, void* d_ws, size_t ws_size,
                              hipStream_t stream){
  const int* node_type = (const int*)d_in[0];
  const int* edge_type = (const int*)d_in[1];
  const int* src       = (const int*)d_in[2];
  const int* dst       = src + E;
  const int* batch     = (const int*)d_in[3];
  const float* nemb = (const float*)d_in[4];
  const float* eemb = (const float*)d_in[5];
  const float* gs[3] = {(const float*)d_in[6], (const float*)d_in[8], (const float*)d_in[10]};
  const float* bs[3] = {(const float*)d_in[7], (const float*)d_in[9], (const float*)d_in[11]};
  const float* go1 = (const float*)d_in[12]; const float* bo1 = (const float*)d_in[13];
  const float* go2 = (const float*)d_in[14]; const float* bo2 = (const float*)d_in[15];
  const float* W1 = (const float*)d_in[16]; const float* B1 = (const float*)d_in[17];
  const float* W2 = (const float*)d_in[18]; const float* B2 = (const float*)d_in[19];
  const float* W3 = (const float*)d_in[20]; const float* B3 = (const float*)d_in[21];
  float* outf = (float*)d_out;

  // ---- workspace layout: [cnt | hg | statsAll] contiguous => single memset ----
  char* p = (char*)d_ws;
  int*   cnt    = (int*)p;              p += (size_t)N * 4;
  float* hg     = (float*)p;            p += (size_t)G * H * 4;
  float* statsA = (float*)p;            p += 5 * 512 * 4;
  size_t zeroBytes = (size_t)p - (size_t)d_ws;
  float* hgW    = (float*)p;            p += (size_t)G * H * 4;
  int*   off    = (int*)p;              p += (size_t)(N + 1) * 4;
  int*   cur    = (int*)p;              p += (size_t)N * 4;
  int*   bsum   = (int*)p;              p += 256 * 4;
  int*   bbase  = (int*)p;              p += 256 * 4;
  int2*  edges_s= (int2*)p;             p += (size_t)E * 8;
  u16*   xb     = (u16*)p;              p += (size_t)N * H * 2;
  u16*   agg    = (u16*)p;              p += (size_t)N * H * 2;
  u16*   xf     = (u16*)p;              p += (size_t)N * 128 * 2;
  u16*   Wt1    = (u16*)p;              p += 65536 * 2;
  u16*   Wt2    = (u16*)p;              p += 32768 * 2;
  u16*   Wt3    = (u16*)p;              p += 16384 * 2;
  float* eembF  = (float*)p;            p += 25600 * 4;
  float* sumsL[5], *sumsqL[5];
  for (int k = 0; k < 5; ++k){ sumsL[k] = statsA + k * 512; sumsqL[k] = statsA + k * 512 + 256; }

  hipMemsetAsync(d_ws, 0, zeroBytes, stream);   // cnt + hg + all stats

  const int preItems = N * 64 + E + 65536 + 32768 + 16384 + 25600;
  k_pre<<<(preItems + 255) / 256, 256, 0, stream>>>(
      node_type, nemb, xb, dst, cnt, W1, W2, W3, eemb, Wt1, Wt2, Wt3, eembF);
  k_scan1<<<NB, 256, 0, stream>>>(cnt, bsum);
  k_scan2<<<1, 256, 0, stream>>>(bsum, bbase);
  k_scan3<<<NB, 256, 0, stream>>>(cnt, bbase, off, cur);
  k_fill<<<(E + 255) / 256, 256, 0, stream>>>(src, dst, edge_type, cur, edges_s);

  // fused 3-layer GNN (gather+stats+BN-apply per layer, grid-synced)
  {
    const float *g0 = gs[0], *b0 = bs[0], *g1 = gs[1], *b1 = bs[1], *g2 = gs[2], *b2 = bs[2];
    void* kargs[] = {(void*)&xb, (void*)&agg, (void*)&edges_s, (void*)&off,
                     (void*)&eembF, (void*)&statsA,
                     (void*)&g0, (void*)&b0, (void*)&g1, (void*)&b1, (void*)&g2, (void*)&b2};
    hipLaunchCooperativeKernel((void*)k_gnn, dim3(GBL), dim3(1024), kargs, 0, stream);
  }

  {
    dim3 pg(G, POOL_S);
    k_pool_seg<<<pg, H, 0, stream>>>(xb, batch, hg);
  }
  k_hgw<<<G, H, 0, stream>>>(hg, W1, B1, hgW);

  const int RB = (N + 127) / 128;   // 391 row blocks

  // GEMM1 (+stats): xb @ W1top + hgW[batch] -> agg (bf16); 128x128 blocks, 2 col tiles
  k_mgemm<256, 256, 0, 1><<<dim3(RB, 2), 256, 0, stream>>>(
      xb, Wt1, hgW, batch, agg, nullptr, sumsL[3], sumsqL[3]);
  k_norm<1, 0><<<(N * 64 + 255) / 256, 256, 0, stream>>>(
      agg, xb, sumsL[3], sumsqL[3], go1, bo1, N * 64, 255);

  // GEMM2 (+stats): Z1b @ W2 + B2 -> xf (bf16, [N,128])
  k_mgemm<256, 128, 1, 1><<<dim3(RB, 1), 256, 0, stream>>>(
      xb, Wt2, B2, nullptr, xf, nullptr, sumsL[4], sumsqL[4]);
  k_norm<1, 0><<<(N * 32 + 255) / 256, 256, 0, stream>>>(
      xf, xb, sumsL[4], sumsqL[4], go2, bo2, N * 32, 127);

  // GEMM3: Z2b @ W3 + B3 -> split fp32 d_out
  k_mgemm<128, 128, 2, 0><<<dim3(RB, 1), 256, 0, stream>>>(
      xb, Wt3, B3, nullptr, nullptr, outf, nullptr, nullptr);
}

// Round 10
// 454.207 us; speedup vs baseline: 1.4710x; 1.4710x over previous
//
#include <hip/hip_runtime.h>
#include <hip/hip_bf16.h>

namespace {

constexpr int N = 50000;
constexpr int E = 300000;
constexpr int G = 256;
constexpr int H = 256;
constexpr float EPS = 1e-5f;
constexpr int NB = (N + 255) / 256;   // 196 scan blocks
constexpr int POOL_S = 16;
constexpr int GBL = 256;              // gather grid: 1 block per CU (132KB LDS)
constexpr int NVB = N / 16;           // 3125 node-groups of 16
constexpr float LOG2E = 1.4426950408889634f;
constexpr float LN2   = 0.6931471805599453f;

typedef unsigned short u16;
typedef __attribute__((ext_vector_type(8))) short bf16x8;
typedef __attribute__((ext_vector_type(4))) float f32x4;

__device__ __forceinline__ float expnabs(float z){
  float r; asm("v_exp_f32 %0, -abs(%1)" : "=v"(r) : "v"(z)); return r;
}
__device__ __forceinline__ float log2f_(float x){
  float r; asm("v_log_f32 %0, %1" : "=v"(r) : "v"(x)); return r;
}
// scaled softplus: input z' = z*log2e; returns log2e*softplus(z)
__device__ __forceinline__ float spw(float zs){
  return fmaxf(zs, 0.f) + log2f_(1.f + expnabs(zs));
}
__device__ __forceinline__ u16 f2b(float f){
  union { float f; unsigned u; } v; v.f = f;
  unsigned r = v.u + 0x7FFF + ((v.u >> 16) & 1);
  return (u16)(r >> 16);
}
__device__ __forceinline__ float b2f(u16 u){
  union { unsigned i; float f; } v; v.i = ((unsigned)u) << 16; return v.f;
}
__device__ __forceinline__ float4 b2f4(ushort4 u){
  return make_float4(b2f(u.x), b2f(u.y), b2f(u.z), b2f(u.w));
}
__device__ __forceinline__ ushort4 f2b4(float4 v){
  ushort4 o; o.x = f2b(v.x); o.y = f2b(v.y); o.z = f2b(v.z); o.w = f2b(v.w);
  return o;
}

// async global->LDS, 16B per lane; LDS dest must be wave-uniform base (+lane*16 implicit)
__device__ __forceinline__ void gl_lds16(const u16* g, u16* l){
  __builtin_amdgcn_global_load_lds(
      (const __attribute__((address_space(1))) unsigned int*)g,
      (__attribute__((address_space(3))) unsigned int*)l, 16, 0, 0);
}

// merged prologue: embed (scaled bf16) | edge histogram | weight conversion | eemb*log2e
__global__ void k_pre(const int* __restrict__ nt, const float* __restrict__ nemb,
                      u16* __restrict__ xb, const int* __restrict__ dst,
                      int* __restrict__ cnt,
                      const float* __restrict__ W1, const float* __restrict__ W2,
                      const float* __restrict__ W3, const float* __restrict__ eemb,
                      u16* __restrict__ Wt1, u16* __restrict__ Wt2,
                      u16* __restrict__ Wt3, float* __restrict__ eembF){
  int idx = blockIdx.x * 256 + threadIdx.x;
  if (idx < N * 64){
    int i = idx >> 6, fq = (idx & 63) << 2;
    float4 v = *(const float4*)(nemb + (size_t)nt[i] * H + fq);
    v.x *= LOG2E; v.y *= LOG2E; v.z *= LOG2E; v.w *= LOG2E;
    *(ushort4*)(xb + (size_t)i * H + fq) = f2b4(v);
    return;
  }
  int j = idx - N * 64;
  if (j < E){ atomicAdd(&cnt[dst[j]], 1); return; }
  j -= E;
  if (j < 65536){ int c = j >> 8, k = j & 255; Wt1[j] = f2b(W1[(size_t)k * 256 + c]); return; }
  j -= 65536;
  if (j < 32768){ int c = j >> 8, k = j & 255; Wt2[j] = f2b(W2[(size_t)k * 128 + c]); return; }
  j -= 32768;
  if (j < 16384){ int c = j >> 7, k = j & 127; Wt3[j] = f2b(W3[(size_t)k * 128 + c]); return; }
  j -= 16384;
  if (j < 25600) eembF[j] = eemb[j] * LOG2E;
}

// ---- CSR scan ----
__global__ void k_scan1(const int* __restrict__ cnt, int* __restrict__ bsum){
  __shared__ int s[256];
  int t = threadIdx.x;
  int i = blockIdx.x * 256 + t;
  s[t] = (i < N) ? cnt[i] : 0;
  __syncthreads();
  for (int d = 128; d > 0; d >>= 1){
    if (t < d) s[t] += s[t + d];
    __syncthreads();
  }
  if (t == 0) bsum[blockIdx.x] = s[0];
}

__global__ void k_scan2(const int* __restrict__ bsum, int* __restrict__ bbase){
  __shared__ int s[256];
  int t = threadIdx.x;
  int orig = (t < NB) ? bsum[t] : 0;
  s[t] = orig;
  __syncthreads();
  for (int d = 1; d < 256; d <<= 1){
    int v = (t >= d) ? s[t - d] : 0;
    __syncthreads();
    s[t] += v;
    __syncthreads();
  }
  bbase[t] = s[t] - orig;   // exclusive
}

__global__ void k_scan3(const int* __restrict__ cnt, const int* __restrict__ bbase,
                        int* __restrict__ off, int* __restrict__ cur){
  __shared__ int s[256];
  int t = threadIdx.x;
  int i = blockIdx.x * 256 + t;
  int v = (i < N) ? cnt[i] : 0;
  s[t] = v;
  __syncthreads();
  for (int d = 1; d < 256; d <<= 1){
    int u = (t >= d) ? s[t - d] : 0;
    __syncthreads();
    s[t] += u;
    __syncthreads();
  }
  int excl = bbase[blockIdx.x] + s[t] - v;
  if (i < N){ off[i] = excl; cur[i] = excl; }
  if (i == N - 1) off[N] = excl + v;   // == E
}

// edges_s[p] = (src*512, et*1024): byte offsets into bf16 xb rows / fp32 eembF rows
__global__ void k_fill(const int* __restrict__ src, const int* __restrict__ dst,
                       const int* __restrict__ et, int* __restrict__ cur,
                       int2* __restrict__ edges_s){
  int e = blockIdx.x * 256 + threadIdx.x;
  if (e >= E) return;
  int d = dst[e];
  int p = atomicAdd(&cur[d], 1);
  edges_s[p] = make_int2(src[e] << 9, et[e] << 10);
}

__device__ __forceinline__ void acc_w(float4& acc, const float4 xs, const float4 es){
  acc.x += spw(xs.x + es.x);
  acc.y += spw(xs.y + es.y);
  acc.z += spw(xs.z + es.z);
  acc.w += spw(xs.w + es.w);
}

// gather + fused BN-stats. 1024 threads = 16 waves; one node per wave per iter.
// eembF (100KB) staged in LDS once per block; per-edge memory = edges_s + random xb row.
// Grid = 256 blocks (1/CU); measured 50.5us/dispatch (session best).
__global__ __launch_bounds__(1024)
void k_gather(const u16* __restrict__ xb, u16* __restrict__ agg,
              const int2* __restrict__ edges_s, const int* __restrict__ off,
              const float* __restrict__ eembF,
              float* __restrict__ sums, float* __restrict__ sumsq){
  __shared__ __align__(16) float elds[25600];     // 100 KB: eembF table
  __shared__ float reds[1024][4];                 // 16 KB
  __shared__ float reds2[1024][4];                // 16 KB
  int tid = threadIdx.x;
  int w = tid >> 6, lane = tid & 63;
  int fx = lane << 3, fe = lane << 4;
  const char* xB = (const char*)xb;
  const char* eL = (const char*)elds;

  // stage eembF -> LDS (6400 float4)
  {
    const float4* s4 = (const float4*)eembF;
    float4* d4 = (float4*)elds;
    for (int t = tid; t < 6400; t += 1024) d4[t] = s4[t];
  }
  __syncthreads();

  float4 ls = make_float4(0.f, 0.f, 0.f, 0.f);
  float4 ls2 = make_float4(0.f, 0.f, 0.f, 0.f);
  for (int vb = blockIdx.x; vb < NVB; vb += GBL){
    int i = vb * 16 + w;
    float4 acc = b2f4(*(const ushort4*)(xB + ((size_t)i << 9) + fx));
    int lo = off[i], hi = off[i + 1];
    int j = lo;
    for (; j + 4 <= hi; j += 4){
      int2 s0 = edges_s[j + 0];
      int2 s1 = edges_s[j + 1];
      int2 s2 = edges_s[j + 2];
      int2 s3 = edges_s[j + 3];
      ushort4 x0 = *(const ushort4*)(xB + s0.x + fx);
      ushort4 x1 = *(const ushort4*)(xB + s1.x + fx);
      ushort4 x2 = *(const ushort4*)(xB + s2.x + fx);
      ushort4 x3 = *(const ushort4*)(xB + s3.x + fx);
      float4 e0 = *(const float4*)(eL + s0.y + fe);
      float4 e1 = *(const float4*)(eL + s1.y + fe);
      float4 e2 = *(const float4*)(eL + s2.y + fe);
      float4 e3 = *(const float4*)(eL + s3.y + fe);
      acc_w(acc, b2f4(x0), e0);
      acc_w(acc, b2f4(x1), e1);
      acc_w(acc, b2f4(x2), e2);
      acc_w(acc, b2f4(x3), e3);
    }
    if (j + 2 <= hi){
      int2 s0 = edges_s[j + 0];
      int2 s1 = edges_s[j + 1];
      ushort4 x0 = *(const ushort4*)(xB + s0.x + fx);
      ushort4 x1 = *(const ushort4*)(xB + s1.x + fx);
      float4 e0 = *(const float4*)(eL + s0.y + fe);
      float4 e1 = *(const float4*)(eL + s1.y + fe);
      acc_w(acc, b2f4(x0), e0);
      acc_w(acc, b2f4(x1), e1);
      j += 2;
    }
    if (j < hi){
      int2 s0 = edges_s[j];
      ushort4 x0 = *(const ushort4*)(xB + s0.x + fx);
      float4 e0 = *(const float4*)(eL + s0.y + fe);
      acc_w(acc, b2f4(x0), e0);
    }
    acc.x *= LN2; acc.y *= LN2; acc.z *= LN2; acc.w *= LN2;
    ls.x += acc.x; ls.y += acc.y; ls.z += acc.z; ls.w += acc.w;
    ls2.x += acc.x * acc.x; ls2.y += acc.y * acc.y;
    ls2.z += acc.z * acc.z; ls2.w += acc.w * acc.w;
    *(ushort4*)((char*)agg + ((size_t)i << 9) + fx) = f2b4(acc);
  }
  reds[tid][0] = ls.x;  reds[tid][1] = ls.y;  reds[tid][2] = ls.z;  reds[tid][3] = ls.w;
  reds2[tid][0] = ls2.x; reds2[tid][1] = ls2.y; reds2[tid][2] = ls2.z; reds2[tid][3] = ls2.w;
  __syncthreads();
  // feature f: contributors waves 0..15 at lane f>>2, component f&3
  if (tid < 256){
    int f = tid;
    float ts = 0.f, ts2 = 0.f;
    #pragma unroll
    for (int w2 = 0; w2 < 16; ++w2){
      int s = w2 * 64 + (f >> 2);
      ts += reds[s][f & 3];
      ts2 += reds2[s][f & 3];
    }
    atomicAdd(&sums[f], ts);
    atomicAdd(&sumsq[f], ts2);
  }
}

// BN-apply, bf16 in -> bf16 out. ACT: softplus. SCALED: output *log2e (for gather input).
template<int ACT, int SCALED>
__global__ void k_norm(const u16* __restrict__ in, u16* __restrict__ outb,
                       const float* __restrict__ sums, const float* __restrict__ sumsq,
                       const float* __restrict__ gamma, const float* __restrict__ beta,
                       int n4, int fmask){
  int idx = blockIdx.x * 256 + threadIdx.x;
  if (idx >= n4) return;
  int base = idx << 2;
  int f = base & fmask;
  float4 s = *(const float4*)(sums + f);
  float4 q = *(const float4*)(sumsq + f);
  float4 g = *(const float4*)(gamma + f);
  float4 bt = *(const float4*)(beta + f);
  float4 v = b2f4(*(const ushort4*)(in + base));
  const float inv = 1.f / N;
  float m, var, a, c;
  m = s.x * inv; var = q.x * inv - m * m; a = g.x * rsqrtf(var + EPS); c = bt.x - m * a; v.x = a * v.x + c;
  m = s.y * inv; var = q.y * inv - m * m; a = g.y * rsqrtf(var + EPS); c = bt.y - m * a; v.y = a * v.y + c;
  m = s.z * inv; var = q.z * inv - m * m; a = g.z * rsqrtf(var + EPS); c = bt.z - m * a; v.z = a * v.z + c;
  m = s.w * inv; var = q.w * inv - m * m; a = g.w * rsqrtf(var + EPS); c = bt.w - m * a; v.w = a * v.w + c;
  if (ACT){
    v.x = spw(v.x * LOG2E); v.y = spw(v.y * LOG2E);
    v.z = spw(v.z * LOG2E); v.w = spw(v.w * LOG2E);
    if (!SCALED){ v.x *= LN2; v.y *= LN2; v.z *= LN2; v.w *= LN2; }
  }
  *(ushort4*)(outb + base) = f2b4(v);
}

// segmented pool over (unscaled) bf16 features: grid (G, POOL_S)
__global__ void k_pool_seg(const u16* __restrict__ xb, const int* __restrict__ batch,
                           float* __restrict__ hg){
  int g = blockIdx.x, sl = blockIdx.y;
  int f = threadIdx.x;
  int lo = 0, hi = N;
  while (lo < hi){ int m = (lo + hi) >> 1; if (batch[m] < g) lo = m + 1; else hi = m; }
  int start = lo;
  lo = 0; hi = N;
  while (lo < hi){ int m = (lo + hi) >> 1; if (batch[m] < g + 1) lo = m + 1; else hi = m; }
  int end = lo;
  int len = end - start;
  int a = start + (int)((long)len * sl / POOL_S);
  int b = start + (int)((long)len * (sl + 1) / POOL_S);
  if (a >= b) return;
  float s = 0.f;
  for (int i = a; i < b; ++i) s += b2f(xb[(size_t)i * H + f]);
  atomicAdd(&hg[g * H + f], s);
}

// hgW[g][c] = sum_k hg[g][k] * W1[256+k][c] + B1[c]
__global__ void k_hgw(const float* __restrict__ hg, const float* __restrict__ W1,
                      const float* __restrict__ B1, float* __restrict__ hgW){
  int g = blockIdx.x, c = threadIdx.x;
  float acc = B1[c];
  for (int k = 0; k < H; ++k)
    acc += hg[g * H + k] * W1[(size_t)(H + k) * H + c];
  hgW[g * H + c] = acc;
}

// LDS-staged double-buffered MFMA GEMM. Block = 128 rows x 128 cols, 4 waves (64x64/wave).
// BK=64 per tile; A/B tiles DMA'd via global_load_lds (linear dest, inverse-XOR-swizzled
// per-lane global source); ds_read_b128 with matching XOR -> <=2-way bank aliasing (free).
// Col tiling via blockIdx.y (GEMM1: 256 cols = 2 y-blocks).
// MODE 0: += hgW[batch[row]] -> bf16; MODE 1: += bias -> bf16; MODE 2: += bias -> split fp32.
template<int K, int NCOUT, int MODE, int STATS>
__global__ __launch_bounds__(256)
void k_mgemm(const u16* __restrict__ Ab, const u16* __restrict__ Wt,
             const float* __restrict__ epi, const int* __restrict__ batch,
             u16* __restrict__ outb, float* __restrict__ outf,
             float* __restrict__ sums, float* __restrict__ sumsq){
  constexpr int T = K / 64;                     // k-tiles
  // smem: A[2][128][64] | B[2][128][64]  (u16), 64 KB total
  __shared__ __align__(16) u16 smem[32768];
  int tid = threadIdx.x;
  int w = tid >> 6, lane = tid & 63;
  int quad = lane >> 4, l15 = lane & 15;
  int wr = w >> 1, wc = w & 1;                  // 2x2 waves
  int rowBase = blockIdx.x * 128 + wr * 64;
  int colTile = blockIdx.y * 128;
  const u16* Ag = Ab + (size_t)blockIdx.x * 128 * K;
  const u16* Bg = Wt + (size_t)colTile * K;

  // stage one 128x64 tile (4 issues of 256 lanes x 16B), source pre-swizzled
  int w6 = tid & 192;                           // wave-uniform wave base
  auto stage = [&](const u16* gbase, u16* lbuf){
    #pragma unroll
    for (int it = 0; it < 4; ++it){
      int p = it * 256 + tid;                   // 16B-unit index
      int row = p >> 3, slot = p & 7;
      const u16* g = gbase + (size_t)row * K + ((slot ^ (row & 7)) << 3);
      gl_lds16(g, smem + ((size_t)((lbuf - smem) + (((it * 256 + w6)) << 3))));
    }
  };

  stage(Ag, smem);                              // A tile 0 -> buf0
  stage(Bg, smem + 16384);                      // B tile 0 -> buf0

  f32x4 acc[4][4] = {};
  int xb7 = l15 & 7;
  for (int tt = 0; tt < T; ++tt){
    if (tt + 1 < T){
      int nb = (tt + 1) & 1;
      stage(Ag + (tt + 1) * 64, smem + nb * 8192);
      stage(Bg + (tt + 1) * 64, smem + 16384 + nb * 8192);
    }
    __syncthreads();                            // drains DMA (vmcnt0) + sync
    const u16* lA = smem + (tt & 1) * 8192;
    const u16* lB = smem + 16384 + (tt & 1) * 8192;
    #pragma unroll
    for (int ks = 0; ks < 2; ++ks){
      int xs = (((ks << 2) | quad) ^ xb7) << 3;
      bf16x8 a[4], b[4];
      #pragma unroll
      for (int t = 0; t < 4; ++t)
        a[t] = *(const bf16x8*)(lA + ((wr * 64 + t * 16 + l15) << 6) + xs);
      #pragma unroll
      for (int u = 0; u < 4; ++u)
        b[u] = *(const bf16x8*)(lB + ((wc * 64 + u * 16 + l15) << 6) + xs);
      #pragma unroll
      for (int t = 0; t < 4; ++t)
        #pragma unroll
        for (int u = 0; u < 4; ++u)
          acc[t][u] = __builtin_amdgcn_mfma_f32_16x16x32_bf16(a[t], b[u], acc[t][u], 0, 0, 0);
    }
    __syncthreads();                            // all reads done before next overwrite
  }

  int colBase = colTile + wc * 64;
  float ls[4] = {0.f, 0.f, 0.f, 0.f};
  float ls2[4] = {0.f, 0.f, 0.f, 0.f};
  #pragma unroll
  for (int t = 0; t < 4; ++t){
    #pragma unroll
    for (int r = 0; r < 4; ++r){
      int row = rowBase + t * 16 + quad * 4 + r;
      if (row >= N) continue;
      int g = (MODE == 0) ? batch[row] : 0;
      #pragma unroll
      for (int u = 0; u < 4; ++u){
        int n = colBase + u * 16 + l15;
        float v = acc[t][u][r];
        if (MODE == 0){
          v += epi[(size_t)g * NCOUT + n];
          outb[(size_t)row * NCOUT + n] = f2b(v);
        } else if (MODE == 1){
          v += epi[n];
          outb[(size_t)row * NCOUT + n] = f2b(v);
        } else {
          v += epi[n];
          if (n < 64) outf[(size_t)row * 64 + n] = v;
          else        outf[(size_t)N * 64 + (size_t)row * 64 + (n - 64)] = v;
        }
        if (STATS){ ls[u] += v; ls2[u] += v * v; }
      }
    }
  }
  if (STATS){
    // reuse tile LDS for the stats reduction (tiles fully consumed, barrier'd)
    float (*reds)[4]  = (float (*)[4])smem;           // 4 KB
    float (*reds2)[4] = (float (*)[4])(smem + 2048);  // next 4 KB
    #pragma unroll
    for (int u = 0; u < 4; ++u){ reds[tid][u] = ls[u]; reds2[tid][u] = ls2[u]; }
    __syncthreads();
    int f = tid;
    if (f < 128){
      int fl = f & 15, fu = (f >> 4) & 3, fw = f >> 6;  // fw = wc
      float ts = 0.f, ts2 = 0.f;
      #pragma unroll
      for (int r2 = 0; r2 < 2; ++r2)
        #pragma unroll
        for (int q = 0; q < 4; ++q){
          int s = (r2 * 2 + fw) * 64 + q * 16 + fl;
          ts += reds[s][fu]; ts2 += reds2[s][fu];
        }
      atomicAdd(&sums[colTile + f], ts);
      atomicAdd(&sumsq[colTile + f], ts2);
    }
  }
}

} // namespace

extern "C" void kernel_launch(void* const* d_in, const int* in_sizes, int n_in,
                              void* d_out, int out_size, void* d_ws, size_t ws_size,
                              hipStream_t stream){
  const int* node_type = (const int*)d_in[0];
  const int* edge_type = (const int*)d_in[1];
  const int* src       = (const int*)d_in[2];
  const int* dst       = src + E;
  const int* batch     = (const int*)d_in[3];
  const float* nemb = (const float*)d_in[4];
  const float* eemb = (const float*)d_in[5];
  const float* gs[3] = {(const float*)d_in[6], (const float*)d_in[8], (const float*)d_in[10]};
  const float* bs[3] = {(const float*)d_in[7], (const float*)d_in[9], (const float*)d_in[11]};
  const float* go1 = (const float*)d_in[12]; const float* bo1 = (const float*)d_in[13];
  const float* go2 = (const float*)d_in[14]; const float* bo2 = (const float*)d_in[15];
  const float* W1 = (const float*)d_in[16]; const float* B1 = (const float*)d_in[17];
  const float* W2 = (const float*)d_in[18]; const float* B2 = (const float*)d_in[19];
  const float* W3 = (const float*)d_in[20]; const float* B3 = (const float*)d_in[21];
  float* outf = (float*)d_out;

  // ---- workspace layout: [cnt | hg | statsAll] contiguous => single memset ----
  char* p = (char*)d_ws;
  int*   cnt    = (int*)p;              p += (size_t)N * 4;
  float* hg     = (float*)p;            p += (size_t)G * H * 4;
  float* statsA = (float*)p;            p += 5 * 512 * 4;
  size_t zeroBytes = (size_t)p - (size_t)d_ws;
  float* hgW    = (float*)p;            p += (size_t)G * H * 4;
  int*   off    = (int*)p;              p += (size_t)(N + 1) * 4;
  int*   cur    = (int*)p;              p += (size_t)N * 4;
  int*   bsum   = (int*)p;              p += 256 * 4;
  int*   bbase  = (int*)p;              p += 256 * 4;
  int2*  edges_s= (int2*)p;             p += (size_t)E * 8;
  u16*   xb     = (u16*)p;              p += (size_t)N * H * 2;
  u16*   agg    = (u16*)p;              p += (size_t)N * H * 2;
  u16*   xf     = (u16*)p;              p += (size_t)N * 128 * 2;
  u16*   Wt1    = (u16*)p;              p += 65536 * 2;
  u16*   Wt2    = (u16*)p;              p += 32768 * 2;
  u16*   Wt3    = (u16*)p;              p += 16384 * 2;
  float* eembF  = (float*)p;            p += 25600 * 4;
  float* sumsL[5], *sumsqL[5];
  for (int k = 0; k < 5; ++k){ sumsL[k] = statsA + k * 512; sumsqL[k] = statsA + k * 512 + 256; }

  hipMemsetAsync(d_ws, 0, zeroBytes, stream);   // cnt + hg + all stats

  const int preItems = N * 64 + E + 65536 + 32768 + 16384 + 25600;
  k_pre<<<(preItems + 255) / 256, 256, 0, stream>>>(
      node_type, nemb, xb, dst, cnt, W1, W2, W3, eemb, Wt1, Wt2, Wt3, eembF);
  k_scan1<<<NB, 256, 0, stream>>>(cnt, bsum);
  k_scan2<<<1, 256, 0, stream>>>(bsum, bbase);
  k_scan3<<<NB, 256, 0, stream>>>(cnt, bbase, off, cur);
  k_fill<<<(E + 255) / 256, 256, 0, stream>>>(src, dst, edge_type, cur, edges_s);

  for (int l = 0; l < 3; ++l){
    k_gather<<<GBL, 1024, 0, stream>>>(xb, agg, edges_s, off, eembF, sumsL[l], sumsqL[l]);
    if (l < 2)
      k_norm<1, 1><<<(N * 64 + 255) / 256, 256, 0, stream>>>(
          agg, xb, sumsL[l], sumsqL[l], gs[l], bs[l], N * 64, 255);
    else  // layer 3: unscaled (feeds pool + GEMM1)
      k_norm<0, 0><<<(N * 64 + 255) / 256, 256, 0, stream>>>(
          agg, xb, sumsL[l], sumsqL[l], gs[l], bs[l], N * 64, 255);
  }

  {
    dim3 pg(G, POOL_S);
    k_pool_seg<<<pg, H, 0, stream>>>(xb, batch, hg);
  }
  k_hgw<<<G, H, 0, stream>>>(hg, W1, B1, hgW);

  const int RB = (N + 127) / 128;   // 391 row blocks

  // GEMM1 (+stats): xb @ W1top + hgW[batch] -> agg (bf16); 128x128 blocks, 2 col tiles
  k_mgemm<256, 256, 0, 1><<<dim3(RB, 2), 256, 0, stream>>>(
      xb, Wt1, hgW, batch, agg, nullptr, sumsL[3], sumsqL[3]);
  k_norm<1, 0><<<(N * 64 + 255) / 256, 256, 0, stream>>>(
      agg, xb, sumsL[3], sumsqL[3], go1, bo1, N * 64, 255);

  // GEMM2 (+stats): Z1b @ W2 + B2 -> xf (bf16, [N,128])
  k_mgemm<256, 128, 1, 1><<<dim3(RB, 1), 256, 0, stream>>>(
      xb, Wt2, B2, nullptr, xf, nullptr, sumsL[4], sumsqL[4]);
  k_norm<1, 0><<<(N * 32 + 255) / 256, 256, 0, stream>>>(
      xf, xb, sumsL[4], sumsqL[4], go2, bo2, N * 32, 127);

  // GEMM3: Z2b @ W3 + B3 -> split fp32 d_out
  k_mgemm<128, 128, 2, 0><<<dim3(RB, 1), 256, 0, stream>>>(
      xb, Wt3, B3, nullptr, nullptr, outf, nullptr, nullptr);
}